// Round 12
// baseline (49.327 us; speedup 1.0000x reference)
//
#include <hip/hip_runtime.h>
#include <hip/hip_bf16.h>

typedef __attribute__((ext_vector_type(2))) _Float16 half2v;
typedef __attribute__((ext_vector_type(8))) _Float16 half8v;
typedef __attribute__((ext_vector_type(4))) float f32x4;

#define NBLK 2048   // multiple of 8 (XCD chunking)

// Fused: out = feat + bias (blocks [0,initB)), Wz f16 pack (blocks [initB, ...))
// Wz column mapping (K-permutation): k = t*32 + gg*8 + j  <->  c = (gg>>1)*8 + t,
// i = (gg&1)*8 + j  (t<8);  t==8: k=256+gg*8+j -> be row gg*8+j (gg<2), 0 pad.
__global__ __launch_bounds__(256) void setup_kernel(
    const float* __restrict__ feat, const float* __restrict__ bias,
    const float* __restrict__ We, const float* __restrict__ be,
    float* __restrict__ out, unsigned short* __restrict__ wp,
    int n_elems, int initB) {
  if ((int)blockIdx.x < initB) {
    int g = blockIdx.x * 256 + threadIdx.x;
    int base = g * 4;
    if (base < n_elems) {
      float4 f = *reinterpret_cast<const float4*>(feat + base);
      const float4* b4 = reinterpret_cast<const float4*>(bias);
      float4 b = b4[g & 3];
      float4 o;
      o.x = f.x + b.x; o.y = f.y + b.y; o.z = f.z + b.z; o.w = f.w + b.w;
      *reinterpret_cast<float4*>(out + base) = o;
    }
  } else {
    int idx = (blockIdx.x - initB) * 256 + threadIdx.x;
    if (idx < 9 * 4 * 16 * 8) {
      int j = idx & 7, n = (idx >> 3) & 15, gg = (idx >> 7) & 3, t = idx >> 9;
      float v = 0.f;
      if (t < 8) {
        int c = (gg >> 1) * 8 + t;
        int i = (gg & 1) * 8 + j;
        v = We[c * 256 + i * 16 + n];
      } else if (gg < 2) {
        v = be[(gg * 8 + j) * 16 + n];
      }
      _Float16 hv = (_Float16)v;
      wp[idx] = __builtin_bit_cast(unsigned short, hv);
    }
  }
}

// A-frag: edge m=lane&15, K-slice k=g*8+j; Z[k] = ef[(g>>1)*8+t] * h[(g&1)*8+j]
// B-frag Bf[t]: lane reads wp[(t*64+lane)*8]. D: col=m, row=g*4+r.
__device__ __forceinline__ void compute_tile(
    float4 E0, float4 E1, float4 H0, float4 H1, int4 dd,
    bool hvalid, int g, int m, const half8v* Bf, float* __restrict__ out) {
  if (!hvalid) { H0 = make_float4(0.f, 0.f, 0.f, 0.f); H1 = H0; }  // kills all K-tiles (E also 0)
  half2v ef2[4], h2[4];
  ef2[0] = half2v{(_Float16)E0.x, (_Float16)E0.y};
  ef2[1] = half2v{(_Float16)E0.z, (_Float16)E0.w};
  ef2[2] = half2v{(_Float16)E1.x, (_Float16)E1.y};
  ef2[3] = half2v{(_Float16)E1.z, (_Float16)E1.w};
  h2[0]  = half2v{(_Float16)H0.x, (_Float16)H0.y};
  h2[1]  = half2v{(_Float16)H0.z, (_Float16)H0.w};
  h2[2]  = half2v{(_Float16)H1.x, (_Float16)H1.y};
  h2[3]  = half2v{(_Float16)H1.z, (_Float16)H1.w};

  f32x4 accA = {0.f, 0.f, 0.f, 0.f};
  f32x4 accB = {0.f, 0.f, 0.f, 0.f};
#pragma unroll
  for (int t = 0; t < 8; ++t) {
    _Float16 ev = ef2[t >> 1][t & 1];
    half2v evb = half2v{ev, ev};
    half2v a0 = evb * h2[0], a1 = evb * h2[1], a2 = evb * h2[2], a3 = evb * h2[3];
    half8v A;
    A[0] = a0[0]; A[1] = a0[1]; A[2] = a1[0]; A[3] = a1[1];
    A[4] = a2[0]; A[5] = a2[1]; A[6] = a3[0]; A[7] = a3[1];
    if (t & 1)
      accB = __builtin_amdgcn_mfma_f32_16x16x32_f16(A, Bf[t], accB, 0, 0, 0);
    else
      accA = __builtin_amdgcn_mfma_f32_16x16x32_f16(A, Bf[t], accA, 0, 0, 0);
  }
  {  // be passthrough K-tile (Z = h[i] at k=256+i), zero pad k>=272
    half2v z = half2v{(_Float16)0.f, (_Float16)0.f};
    half2v b0 = (g < 2) ? h2[0] : z, b1 = (g < 2) ? h2[1] : z;
    half2v b2 = (g < 2) ? h2[2] : z, b3 = (g < 2) ? h2[3] : z;
    half8v A;
    A[0] = b0[0]; A[1] = b0[1]; A[2] = b1[0]; A[3] = b1[1];
    A[4] = b2[0]; A[5] = b2[1]; A[6] = b3[0]; A[7] = b3[1];
    accB = __builtin_amdgcn_mfma_f32_16x16x32_f16(A, Bf[8], accB, 0, 0, 0);
  }
  f32x4 acc;
  acc[0] = accA[0] + accB[0]; acc[1] = accA[1] + accB[1];
  acc[2] = accA[2] + accB[2]; acc[3] = accA[3] + accB[3];

  // fast path: whole tile single dst (sorted => endpoints equal)
  int nA = __shfl(dd.x, 0, 64);
  int nB = __shfl(dd.w, 48, 64);
  if (nA == nB) {
    float v = acc[0] + acc[1] + acc[2] + acc[3];
    v += __shfl_xor(v, 32, 64);
    v += __shfl_xor(v, 16, 64);
    if (g == 0) unsafeAtomicAdd(out + (size_t)nA * 16 + m, v);
    return;
  }
  // general path: per-group run-combine, one atomic per run
  float run = acc[0];
  int cur = dd.x;
  if (dd.y == cur) run += acc[1];
  else { unsafeAtomicAdd(out + (size_t)cur * 16 + m, run); cur = dd.y; run = acc[1]; }
  if (dd.z == cur) run += acc[2];
  else { unsafeAtomicAdd(out + (size_t)cur * 16 + m, run); cur = dd.z; run = acc[2]; }
  if (dd.w == cur) run += acc[3];
  else { unsafeAtomicAdd(out + (size_t)cur * 16 + m, run); cur = dd.w; run = acc[3]; }
  unsafeAtomicAdd(out + (size_t)cur * 16 + m, run);
}

// XCD-chunked persistent waves. KEY CHANGE vs R9: the dependent feat[src] gather
// for tile t+1 is issued AFTER compute(t), not before — so its src-wait never
// stalls the MFMA region, and the gather latency hides under the next iteration's
// independent-issue block + compute prologue. src is prefetched 2 tiles ahead.
__global__ __launch_bounds__(256) void edge_mfma_kernel(
    const float* __restrict__ feat, const float* __restrict__ efeat,
    const int* __restrict__ src, const int* __restrict__ dst,
    const unsigned short* __restrict__ wp,
    float* __restrict__ out, int E) {
  int wid = threadIdx.x >> 6;
  int lane = threadIdx.x & 63;
  int g = lane >> 4;
  int m = lane & 15;
  int p = g >> 1;
  int hh = g & 1;

  int ntiles = (E + 15) >> 4;
  const bool partialF = (E & 15) != 0;
  const int lastT = ntiles - 1;

  int T8 = (ntiles + 7) >> 3;
  int xcd = blockIdx.x & 7;
  int wic = (blockIdx.x >> 3) * 4 + wid;
  int CW = (gridDim.x >> 3) * 4;
  int cs = xcd * T8;
  int ce = min(cs + T8, ntiles);

  int t = cs + wic;
  if (t >= ce) return;

  half8v Bf[9];
#pragma unroll
  for (int tt = 0; tt < 9; ++tt)
    Bf[tt] = *reinterpret_cast<const half8v*>(wp + (unsigned)(tt * 64 + lane) * 8);

  const float4* ef4 = reinterpret_cast<const float4*>(efeat);
  const float4* f4  = reinterpret_cast<const float4*>(feat);
  const int4*   d4  = reinterpret_cast<const int4*>(dst);

  // ---- prologue: tile t fully (serial gather once), src 1- and 2-ahead ----
  float4 E0, E1, H0, H1;
  int4 dd;
  bool v_cur = (t * 16 + m) < E;
  {
    int ec = min(t * 16 + m, E - 1);
    E0 = ef4[(unsigned)ec * 4 + p * 2]; E1 = ef4[(unsigned)ec * 4 + p * 2 + 1];
    if (!v_cur) { E0 = make_float4(0.f, 0.f, 0.f, 0.f); E1 = E0; }
    int s = src[ec];
    H0 = f4[(unsigned)s * 4 + hh * 2]; H1 = f4[(unsigned)s * 4 + hh * 2 + 1];
    if (__builtin_expect(partialF && t == lastT, 0)) {
      int b = t * 16 + g * 4;
      dd.x = dst[min(b + 0, E - 1)]; dd.y = dst[min(b + 1, E - 1)];
      dd.z = dst[min(b + 2, E - 1)]; dd.w = dst[min(b + 3, E - 1)];
    } else {
      dd = d4[(unsigned)t * 4 + g];
    }
  }
  int t1 = t + CW;
  int t2 = t1 + CW;
  int s1 = (t1 < ce) ? src[min(t1 * 16 + m, E - 1)] : 0;   // src for t+1
  int s2 = (t2 < ce) ? src[min(t2 * 16 + m, E - 1)] : 0;   // src for t+2

  while (t1 < ce) {
    // ---- issue independent loads for t1 (E, dd) and src for t+3 ----
    float4 E0n, E1n;
    int4 ddn;
    bool v_n = (t1 * 16 + m) < E;
    {
      int ec = min(t1 * 16 + m, E - 1);
      E0n = ef4[(unsigned)ec * 4 + p * 2]; E1n = ef4[(unsigned)ec * 4 + p * 2 + 1];
      if (!v_n) { E0n = make_float4(0.f, 0.f, 0.f, 0.f); E1n = E0n; }
      if (__builtin_expect(partialF && t1 == lastT, 0)) {
        int b = t1 * 16 + g * 4;
        ddn.x = dst[min(b + 0, E - 1)]; ddn.y = dst[min(b + 1, E - 1)];
        ddn.z = dst[min(b + 2, E - 1)]; ddn.w = dst[min(b + 3, E - 1)];
      } else {
        ddn = d4[(unsigned)t1 * 4 + g];
      }
    }
    int t3 = t2 + CW;
    int s3 = src[min(min(t3, ce - 1) * 16 + m, E - 1)];   // clamped; dead if loop exits
    __builtin_amdgcn_sched_barrier(0);

    // ---- compute current tile (H was gathered one iteration ago) ----
    compute_tile(E0, E1, H0, H1, dd, v_cur, g, m, Bf, out);
    __builtin_amdgcn_sched_barrier(0);

    // ---- dependent gather for t1 AFTER compute: s1 is >=2 iterations old ----
    H0 = f4[(unsigned)s1 * 4 + hh * 2];
    H1 = f4[(unsigned)s1 * 4 + hh * 2 + 1];

    E0 = E0n; E1 = E1n; dd = ddn; v_cur = v_n;
    s1 = s2; s2 = s3;
    t = t1; t1 = t2; t2 = t3;
  }
  compute_tile(E0, E1, H0, H1, dd, v_cur, g, m, Bf, out);
}

extern "C" void kernel_launch(void* const* d_in, const int* in_sizes, int n_in,
                              void* d_out, int out_size, void* d_ws, size_t ws_size,
                              hipStream_t stream) {
  const float* feat  = (const float*)d_in[0];
  const float* efeat = (const float*)d_in[1];
  const float* We    = (const float*)d_in[2];
  const float* be    = (const float*)d_in[3];
  const float* bias  = (const float*)d_in[4];
  const int*   src   = (const int*)d_in[5];
  const int*   dst   = (const int*)d_in[6];
  float* out = (float*)d_out;

  int E = in_sizes[5];
  int n_elems = out_size;  // 50000*16

  int groups = (n_elems + 3) / 4;
  int initB = (groups + 255) / 256;
  int prepB = (9 * 4 * 16 * 8 + 255) / 256;
  setup_kernel<<<initB + prepB, 256, 0, stream>>>(feat, bias, We, be, out,
                                                  (unsigned short*)d_ws, n_elems, initB);

  edge_mfma_kernel<<<NBLK, 256, 0, stream>>>(feat, efeat, src, dst,
                                             (const unsigned short*)d_ws, out, E);
}

// Round 13
// 42.670 us; speedup vs baseline: 1.1560x; 1.1560x over previous
//
#include <hip/hip_runtime.h>

typedef __attribute__((ext_vector_type(2))) _Float16 half2v;
typedef __attribute__((ext_vector_type(8))) _Float16 half8v;
typedef __attribute__((ext_vector_type(4))) float f32x4;

#define NBLK 2048
#define WT (NBLK * 4)            // total waves in phase A
#define WP_ELEMS (9 * 4 * 16 * 8)
#define RP_OFF 16384             // row_ptr byte offset in d_ws
#define MS_OFF (16384 + 262144)  // m-buffer byte offset in d_ws

// Setup: (a) Wz f16 pack, (b) row_ptr[n] = lower_bound(dst, n).
// Wz column mapping: k = t*32 + gg*8 + j <-> c = (gg>>1)*8 + t, i = (gg&1)*8 + j
// (t<8); t==8: be row gg*8+j (gg<2), 0 pad.
__global__ __launch_bounds__(256) void setup_kernel(
    const float* __restrict__ We, const float* __restrict__ be,
    const int* __restrict__ dst,
    unsigned short* __restrict__ wp, int* __restrict__ rp,
    int E, int N) {
  int idx = blockIdx.x * 256 + threadIdx.x;
  if (idx < WP_ELEMS) {
    int j = idx & 7, n = (idx >> 3) & 15, gg = (idx >> 7) & 3, t = idx >> 9;
    float v = 0.f;
    if (t < 8) {
      int c = (gg >> 1) * 8 + t;
      int i = (gg & 1) * 8 + j;
      v = We[c * 256 + i * 16 + n];
    } else if (gg < 2) {
      v = be[(gg * 8 + j) * 16 + n];
    }
    _Float16 hv = (_Float16)v;
    wp[idx] = __builtin_bit_cast(unsigned short, hv);
  }
  if (idx <= N) {
    int lo = 0, hi = E;
    while (lo < hi) {
      int mid = (lo + hi) >> 1;
      if (dst[mid] < idx) lo = mid + 1; else hi = mid;
    }
    rp[idx] = lo;
  }
}

// LDS per wave per buf: ef16[16 edges][16ch] stride 48B (768B) + hf16 same at +768.
// Write (lane l, edge el=l>>2, q=l&3): 8B (4 halves, chans q*4..+3) at el*48+q*8.
// Read (lane g,m): ef chans p*8..+7 at m*48+p*16; hf chans hh*8..+7 at 768+m*48+hh*16.
__device__ __forceinline__ void cvt_mask_write(char* bufb, int lane,
                                               float4 ve, float4 vh, bool vld) {
  if (!vld) { ve = make_float4(0.f, 0.f, 0.f, 0.f); vh = ve; }
  half2v e0 = half2v{(_Float16)ve.x, (_Float16)ve.y};
  half2v e1 = half2v{(_Float16)ve.z, (_Float16)ve.w};
  half2v h0 = half2v{(_Float16)vh.x, (_Float16)vh.y};
  half2v h1 = half2v{(_Float16)vh.z, (_Float16)vh.w};
  uint2 ew, hw;
  ew.x = __builtin_bit_cast(unsigned, e0); ew.y = __builtin_bit_cast(unsigned, e1);
  hw.x = __builtin_bit_cast(unsigned, h0); hw.y = __builtin_bit_cast(unsigned, h1);
  int el = lane >> 2, q = lane & 3;
  *reinterpret_cast<uint2*>(bufb + el * 48 + q * 8) = ew;
  *reinterpret_cast<uint2*>(bufb + 768 + el * 48 + q * 8) = hw;
}

// compute tile from LDS frags, store D-fragment as f16: ms[tile*256 + lane*4 + r]
__device__ __forceinline__ void compute_store(
    unsigned short* __restrict__ ms, int tile, const char* bufb,
    int g, int m, int lane, const half8v* Bf) {
  int p = g >> 1, hh = g & 1;
  half8v efr = *reinterpret_cast<const half8v*>(bufb + m * 48 + p * 16);
  half8v hfr = *reinterpret_cast<const half8v*>(bufb + 768 + m * 48 + hh * 16);
  half2v ef2[4], h2[4];
#pragma unroll
  for (int j = 0; j < 4; ++j) {
    ef2[j] = half2v{efr[2 * j], efr[2 * j + 1]};
    h2[j]  = half2v{hfr[2 * j], hfr[2 * j + 1]};
  }
  f32x4 accA = {0.f, 0.f, 0.f, 0.f};
  f32x4 accB = {0.f, 0.f, 0.f, 0.f};
#pragma unroll
  for (int t = 0; t < 8; ++t) {
    _Float16 ev = ef2[t >> 1][t & 1];
    half2v evb = half2v{ev, ev};
    half2v a0 = evb * h2[0], a1 = evb * h2[1], a2 = evb * h2[2], a3 = evb * h2[3];
    half8v A;
    A[0] = a0[0]; A[1] = a0[1]; A[2] = a1[0]; A[3] = a1[1];
    A[4] = a2[0]; A[5] = a2[1]; A[6] = a3[0]; A[7] = a3[1];
    if (t & 1)
      accB = __builtin_amdgcn_mfma_f32_16x16x32_f16(A, Bf[t], accB, 0, 0, 0);
    else
      accA = __builtin_amdgcn_mfma_f32_16x16x32_f16(A, Bf[t], accA, 0, 0, 0);
  }
  {  // be passthrough K-tile
    half2v z = half2v{(_Float16)0.f, (_Float16)0.f};
    half2v b0 = (g < 2) ? h2[0] : z, b1 = (g < 2) ? h2[1] : z;
    half2v b2 = (g < 2) ? h2[2] : z, b3 = (g < 2) ? h2[3] : z;
    half8v A;
    A[0] = b0[0]; A[1] = b0[1]; A[2] = b1[0]; A[3] = b1[1];
    A[4] = b2[0]; A[5] = b2[1]; A[6] = b3[0]; A[7] = b3[1];
    accB = __builtin_amdgcn_mfma_f32_16x16x32_f16(A, Bf[8], accB, 0, 0, 0);
  }
  half2v lo = half2v{(_Float16)(accA[0] + accB[0]), (_Float16)(accA[1] + accB[1])};
  half2v hi = half2v{(_Float16)(accA[2] + accB[2]), (_Float16)(accA[3] + accB[3])};
  uint2 w;
  w.x = __builtin_bit_cast(unsigned, lo);
  w.y = __builtin_bit_cast(unsigned, hi);
  *reinterpret_cast<uint2*>(ms + (size_t)tile * 256 + lane * 4) = w;
}

// Phase A: minimal-line loads. Per tile: 1 E-load (16 lines), 1 H-gather
// (16 lines = 16 feat rows), 1 src (1 line), 1 ms store. LDS redistributes.
__global__ __launch_bounds__(256) void edge_gemm_kernel(
    const float* __restrict__ feat, const float* __restrict__ efeat,
    const int* __restrict__ src, const unsigned short* __restrict__ wp,
    unsigned short* __restrict__ ms, int E) {
  __shared__ __align__(16) char lds[4][2][1536];
  int wid = threadIdx.x >> 6;
  int lane = threadIdx.x & 63;
  int g = lane >> 4, m = lane & 15;
  int el = lane >> 2, q = lane & 3;

  int ntiles = (E + 15) >> 4;
  int wave = blockIdx.x * 4 + wid;
  if (wave >= ntiles) return;

  half8v Bf[9];
#pragma unroll
  for (int t = 0; t < 9; ++t)
    Bf[t] = *reinterpret_cast<const half8v*>(wp + (unsigned)(t * 64 + lane) * 8);

  // ---- prologue: tile t fully staged into buf0; src for t1 prefetched ----
  int t = wave;
  {
    int eg = min(t * 16 + el, E - 1);
    int s  = src[eg];
    float4 ve = *reinterpret_cast<const float4*>(efeat + (size_t)eg * 16 + q * 4);
    float4 vh = *reinterpret_cast<const float4*>(feat + (size_t)s * 16 + q * 4);
    cvt_mask_write(&lds[wid][0][0], lane, ve, vh, (t * 16 + el) < E);
  }
  int t1 = t + WT;
  int s1 = (t1 < ntiles) ? src[min(t1 * 16 + el, E - 1)] : 0;
  int b = 0;

  while (t1 < ntiles) {
    int t2 = t1 + WT;
    // ---- issue: src(t2), E(t1), H(t1 via s1, loaded last iter) ----
    int s2 = src[min(min(t2, ntiles - 1) * 16 + el, E - 1)];
    int eg1 = min(t1 * 16 + el, E - 1);
    float4 ve = *reinterpret_cast<const float4*>(efeat + (size_t)eg1 * 16 + q * 4);
    float4 vh = *reinterpret_cast<const float4*>(feat + (size_t)s1 * 16 + q * 4);
    __builtin_amdgcn_sched_barrier(0);

    // ---- compute current tile from LDS buf b, store ms(t) ----
    compute_store(ms, t, &lds[wid][b][0], g, m, lane, Bf);

    // ---- wait loads (store may stay outstanding), stage t1 into buf b^1 ----
    asm volatile("s_waitcnt vmcnt(1)" ::: "memory");
    __builtin_amdgcn_sched_barrier(0);
    cvt_mask_write(&lds[wid][b ^ 1][0], lane, ve, vh, (t1 * 16 + el) < E);

    s1 = s2;
    t = t1; t1 = t2; b ^= 1;
  }
  compute_store(ms, t, &lds[wid][b][0], g, m, lane, Bf);
}

// fragment-layout index of m[e][c]: (e>>4)*256 + ((e>>2)&3)*64 + c*4 + (e&3)
__device__ __forceinline__ float ms_at(const unsigned short* ms, int e, int c) {
  unsigned short u = ms[((e >> 4) << 8) + (((e >> 2) & 3) << 6) + (c << 2) + (e & 3)];
  return (float)__builtin_bit_cast(_Float16, u);
}

// Phase B: one 16-lane group per node; walk edge run, 4-edge (8B) vector loads.
__global__ __launch_bounds__(256) void segsum_kernel(
    const float* __restrict__ feat, const float* __restrict__ bias,
    const unsigned short* __restrict__ ms, const int* __restrict__ rp,
    float* __restrict__ out, int N) {
  int n = blockIdx.x * 16 + (threadIdx.x >> 4);
  int c = threadIdx.x & 15;
  if (n >= N) return;
  int lo = rp[n], hi = rp[n + 1];
  float sum = 0.f;
  int e = lo;
  while (e < hi && (e & 3)) { sum += ms_at(ms, e, c); ++e; }
  while (e + 4 <= hi) {
    const uint2 v = *reinterpret_cast<const uint2*>(
        ms + ((e >> 4) << 8) + (((e >> 2) & 3) << 6) + (c << 2));
    half2v x = __builtin_bit_cast(half2v, v.x);
    half2v y = __builtin_bit_cast(half2v, v.y);
    sum += (float)x[0] + (float)x[1] + (float)y[0] + (float)y[1];
    e += 4;
  }
  while (e < hi) { sum += ms_at(ms, e, c); ++e; }
  out[n * 16 + c] = sum + feat[n * 16 + c] + bias[c];
}

extern "C" void kernel_launch(void* const* d_in, const int* in_sizes, int n_in,
                              void* d_out, int out_size, void* d_ws, size_t ws_size,
                              hipStream_t stream) {
  const float* feat  = (const float*)d_in[0];
  const float* efeat = (const float*)d_in[1];
  const float* We    = (const float*)d_in[2];
  const float* be    = (const float*)d_in[3];
  const float* bias  = (const float*)d_in[4];
  const int*   src   = (const int*)d_in[5];
  const int*   dst   = (const int*)d_in[6];
  float* out = (float*)d_out;

  int E = in_sizes[5];
  int N = out_size / 16;

  unsigned short* wp = (unsigned short*)d_ws;
  int* rp = (int*)((char*)d_ws + RP_OFF);
  unsigned short* ms = (unsigned short*)((char*)d_ws + MS_OFF);

  int setup_items = (N + 1) > WP_ELEMS ? (N + 1) : WP_ELEMS;
  setup_kernel<<<(setup_items + 255) / 256, 256, 0, stream>>>(We, be, dst, wp, rp, E, N);

  int ntiles = (E + 15) / 16;
  int blocksA = min(NBLK, (ntiles + 3) / 4);
  edge_gemm_kernel<<<blocksA, 256, 0, stream>>>(feat, efeat, src, wp, ms, E);

  int blocksB = (N + 15) / 16;
  segsum_kernel<<<blocksB, 256, 0, stream>>>(feat, bias, ms, rp, out, N);
}

// Round 14
// 42.169 us; speedup vs baseline: 1.1697x; 1.0119x over previous
//
#include <hip/hip_runtime.h>

typedef __attribute__((ext_vector_type(2))) _Float16 half2v;
typedef __attribute__((ext_vector_type(8))) _Float16 half8v;
typedef __attribute__((ext_vector_type(4))) float f32x4;

#define NBLK 1024
#define WP_ELEMS (9 * 4 * 16 * 8)
#define RP_OFF 16384             // row_ptr byte offset in d_ws
#define MS_OFF (16384 + 262144)  // m-buffer byte offset in d_ws

// Setup: (a) Wz f16 pack, (b) row_ptr[n] = lower_bound(dst, n).
// Wz column mapping: k = t*32 + gg*8 + j <-> c = (gg>>1)*8 + t, i = (gg&1)*8 + j
// (t<8); t==8: be row gg*8+j (gg<2), 0 pad.
__global__ __launch_bounds__(256) void setup_kernel(
    const float* __restrict__ We, const float* __restrict__ be,
    const int* __restrict__ dst,
    unsigned short* __restrict__ wp, int* __restrict__ rp,
    int E, int N) {
  int idx = blockIdx.x * 256 + threadIdx.x;
  if (idx < WP_ELEMS) {
    int j = idx & 7, n = (idx >> 3) & 15, gg = (idx >> 7) & 3, t = idx >> 9;
    float v = 0.f;
    if (t < 8) {
      int c = (gg >> 1) * 8 + t;
      int i = (gg & 1) * 8 + j;
      v = We[c * 256 + i * 16 + n];
    } else if (gg < 2) {
      v = be[(gg * 8 + j) * 16 + n];
    }
    _Float16 hv = (_Float16)v;
    wp[idx] = __builtin_bit_cast(unsigned short, hv);
  }
  if (idx <= N) {
    int lo = 0, hi = E;
    while (lo < hi) {
      int mid = (lo + hi) >> 1;
      if (dst[mid] < idx) lo = mid + 1; else hi = mid;
    }
    rp[idx] = lo;
  }
}

// A-frag: edge m=lane&15, K-slice k=g*8+j; Z[k] = ef[(g>>1)*8+t] * h[(g&1)*8+j]
// B-frag Bf[t]: lane reads wp[(t*64+lane)*8]. D: col=m, row=g*4+r.
// Store D-fragment as f16: ms[tile*256 + lane*4 + r] -> one 8B store per lane.
__device__ __forceinline__ void compute_store(
    unsigned short* __restrict__ ms, int tile,
    float4 E0, float4 E1, float4 H0, float4 H1, bool valid,
    int g, int lane, const half8v* Bf) {
  if (!valid) {
    E0 = make_float4(0.f, 0.f, 0.f, 0.f); E1 = E0; H0 = E0; H1 = E0;
  }
  half2v ef2[4], h2[4];
  ef2[0] = half2v{(_Float16)E0.x, (_Float16)E0.y};
  ef2[1] = half2v{(_Float16)E0.z, (_Float16)E0.w};
  ef2[2] = half2v{(_Float16)E1.x, (_Float16)E1.y};
  ef2[3] = half2v{(_Float16)E1.z, (_Float16)E1.w};
  h2[0]  = half2v{(_Float16)H0.x, (_Float16)H0.y};
  h2[1]  = half2v{(_Float16)H0.z, (_Float16)H0.w};
  h2[2]  = half2v{(_Float16)H1.x, (_Float16)H1.y};
  h2[3]  = half2v{(_Float16)H1.z, (_Float16)H1.w};

  f32x4 accA = {0.f, 0.f, 0.f, 0.f};
  f32x4 accB = {0.f, 0.f, 0.f, 0.f};
#pragma unroll
  for (int t = 0; t < 8; ++t) {
    _Float16 ev = ef2[t >> 1][t & 1];
    half2v evb = half2v{ev, ev};
    half2v a0 = evb * h2[0], a1 = evb * h2[1], a2 = evb * h2[2], a3 = evb * h2[3];
    half8v A;
    A[0] = a0[0]; A[1] = a0[1]; A[2] = a1[0]; A[3] = a1[1];
    A[4] = a2[0]; A[5] = a2[1]; A[6] = a3[0]; A[7] = a3[1];
    if (t & 1)
      accB = __builtin_amdgcn_mfma_f32_16x16x32_f16(A, Bf[t], accB, 0, 0, 0);
    else
      accA = __builtin_amdgcn_mfma_f32_16x16x32_f16(A, Bf[t], accA, 0, 0, 0);
  }
  {  // be passthrough K-tile (Z = h[i] at k=256+i), zero pad k>=272
    half2v z = half2v{(_Float16)0.f, (_Float16)0.f};
    half2v b0 = (g < 2) ? h2[0] : z, b1 = (g < 2) ? h2[1] : z;
    half2v b2 = (g < 2) ? h2[2] : z, b3 = (g < 2) ? h2[3] : z;
    half8v A;
    A[0] = b0[0]; A[1] = b0[1]; A[2] = b1[0]; A[3] = b1[1];
    A[4] = b2[0]; A[5] = b2[1]; A[6] = b3[0]; A[7] = b3[1];
    accB = __builtin_amdgcn_mfma_f32_16x16x32_f16(A, Bf[8], accB, 0, 0, 0);
  }
  half2v lo = half2v{(_Float16)(accA[0] + accB[0]), (_Float16)(accA[1] + accB[1])};
  half2v hi = half2v{(_Float16)(accA[2] + accB[2]), (_Float16)(accA[3] + accB[3])};
  uint2 w;
  w.x = __builtin_bit_cast(unsigned, lo);
  w.y = __builtin_bit_cast(unsigned, hi);
  *reinterpret_cast<uint2*>(ms + (size_t)tile * 256 + lane * 4) = w;
}

// Phase A: hand-built DEPTH-2 pipeline. Per iter: issue group(t+2)=[src(t+4),
// E(t+2)x2, H(t+2)x2] (H addressed by src loaded 2 iters ago), compute tile t
// (data issued 2 iters ago), store, then s_waitcnt vmcnt(7): FIFO retires
// group(t+1) fully while group(t+2)+2 stores stay in flight.
__global__ __launch_bounds__(256) void edge_gemm_kernel(
    const float* __restrict__ feat, const float* __restrict__ efeat,
    const int* __restrict__ src, const unsigned short* __restrict__ wp,
    unsigned short* __restrict__ ms, int E) {
  int wid = threadIdx.x >> 6;
  int lane = threadIdx.x & 63;
  int g = lane >> 4, m = lane & 15;
  int p = g >> 1, hh = g & 1;

  int ntiles = (E + 15) >> 4;
  int CW = gridDim.x * 4;
  int t = blockIdx.x * 4 + wid;
  if (t >= ntiles) return;

  half8v Bf[9];
#pragma unroll
  for (int tt = 0; tt < 9; ++tt)
    Bf[tt] = *reinterpret_cast<const half8v*>(wp + (unsigned)(tt * 64 + lane) * 8);

  const float4* ef4 = reinterpret_cast<const float4*>(efeat);
  const float4* f4  = reinterpret_cast<const float4*>(feat);

  // ---- prologue: slot A (tile t) serial ----
  float4 EA0, EA1, HA0, HA1; bool vA;
  {
    int ec = min(t * 16 + m, E - 1); vA = (t * 16 + m) < E;
    EA0 = ef4[(unsigned)ec * 4 + p * 2]; EA1 = ef4[(unsigned)ec * 4 + p * 2 + 1];
    int s = src[ec];
    HA0 = f4[(unsigned)s * 4 + hh * 2]; HA1 = f4[(unsigned)s * 4 + hh * 2 + 1];
  }
  int t1 = t + CW;
  if (t1 >= ntiles) {
    compute_store(ms, t, EA0, EA1, HA0, HA1, vA, g, lane, Bf);
    return;
  }
  // ---- slot B (tile t1) + src 2- and 3-ahead ----
  float4 EB0, EB1, HB0, HB1; bool vB;
  {
    int ec = min(t1 * 16 + m, E - 1); vB = (t1 * 16 + m) < E;
    EB0 = ef4[(unsigned)ec * 4 + p * 2]; EB1 = ef4[(unsigned)ec * 4 + p * 2 + 1];
    int s = src[ec];
    HB0 = f4[(unsigned)s * 4 + hh * 2]; HB1 = f4[(unsigned)s * 4 + hh * 2 + 1];
  }
  int t2 = t1 + CW;
  int t3 = t2 + CW;
  int s2 = src[min(min(t2, ntiles - 1) * 16 + m, E - 1)];
  int s3 = src[min(min(t3, ntiles - 1) * 16 + m, E - 1)];
  asm volatile("s_waitcnt vmcnt(0)" ::: "memory");
  __builtin_amdgcn_sched_barrier(0);

  while (t2 < ntiles) {
    // ---- issue group(t2) into slot C; sfar = src(t4) ----
    float4 EC0, EC1, HC0, HC1; bool vC;
    int t4 = t3 + CW;
    int s4 = src[min(min(t4, ntiles - 1) * 16 + m, E - 1)];
    {
      int ec = min(t2 * 16 + m, E - 1); vC = (t2 * 16 + m) < E;
      EC0 = ef4[(unsigned)ec * 4 + p * 2]; EC1 = ef4[(unsigned)ec * 4 + p * 2 + 1];
      HC0 = f4[(unsigned)s2 * 4 + hh * 2]; HC1 = f4[(unsigned)s2 * 4 + hh * 2 + 1];
    }
    __builtin_amdgcn_sched_barrier(0);

    // ---- compute tile t (slot A, data >=2 iters old), store ms(t) ----
    compute_store(ms, t, EA0, EA1, HA0, HA1, vA, g, lane, Bf);
    __builtin_amdgcn_sched_barrier(0);

    // ---- counted drain: retire group(t+1); leave group(t+2)+2 stores in flight ----
    asm volatile("s_waitcnt vmcnt(7)" ::: "memory");
    __builtin_amdgcn_sched_barrier(0);

    // ---- rotate ----
    EA0 = EB0; EA1 = EB1; HA0 = HB0; HA1 = HB1; vA = vB;
    EB0 = EC0; EB1 = EC1; HB0 = HC0; HB1 = HC1; vB = vC;
    s2 = s3; s3 = s4;
    t = t1; t1 = t2; t2 = t3; t3 = t4;
  }
  // ---- drain: tiles t (A) and t1 (B) ----
  asm volatile("s_waitcnt vmcnt(0)" ::: "memory");
  __builtin_amdgcn_sched_barrier(0);
  compute_store(ms, t, EA0, EA1, HA0, HA1, vA, g, lane, Bf);
  if (t1 < ntiles)
    compute_store(ms, t1, EB0, EB1, HB0, HB1, vB, g, lane, Bf);
}

// fragment-layout index of m[e][c]: (e>>4)*256 + ((e>>2)&3)*64 + c*4 + (e&3)
__device__ __forceinline__ float ms_at(const unsigned short* ms, int e, int c) {
  unsigned short u = ms[((e >> 4) << 8) + (((e >> 2) & 3) << 6) + (c << 2) + (e & 3)];
  return (float)__builtin_bit_cast(_Float16, u);
}

// Phase B: one 16-lane group per node; walk edge run, 4-edge (8B) vector loads.
__global__ __launch_bounds__(256) void segsum_kernel(
    const float* __restrict__ feat, const float* __restrict__ bias,
    const unsigned short* __restrict__ ms, const int* __restrict__ rp,
    float* __restrict__ out, int N) {
  int n = blockIdx.x * 16 + (threadIdx.x >> 4);
  int c = threadIdx.x & 15;
  if (n >= N) return;
  int lo = rp[n], hi = rp[n + 1];
  float sum = 0.f;
  int e = lo;
  while (e < hi && (e & 3)) { sum += ms_at(ms, e, c); ++e; }
  while (e + 4 <= hi) {
    const uint2 v = *reinterpret_cast<const uint2*>(
        ms + ((e >> 4) << 8) + (((e >> 2) & 3) << 6) + (c << 2));
    half2v x = __builtin_bit_cast(half2v, v.x);
    half2v y = __builtin_bit_cast(half2v, v.y);
    sum += (float)x[0] + (float)x[1] + (float)y[0] + (float)y[1];
    e += 4;
  }
  while (e < hi) { sum += ms_at(ms, e, c); ++e; }
  out[n * 16 + c] = sum + feat[n * 16 + c] + bias[c];
}

extern "C" void kernel_launch(void* const* d_in, const int* in_sizes, int n_in,
                              void* d_out, int out_size, void* d_ws, size_t ws_size,
                              hipStream_t stream) {
  const float* feat  = (const float*)d_in[0];
  const float* efeat = (const float*)d_in[1];
  const float* We    = (const float*)d_in[2];
  const float* be    = (const float*)d_in[3];
  const float* bias  = (const float*)d_in[4];
  const int*   src   = (const int*)d_in[5];
  const int*   dst   = (const int*)d_in[6];
  float* out = (float*)d_out;

  int E = in_sizes[5];
  int N = out_size / 16;

  unsigned short* wp = (unsigned short*)d_ws;
  int* rp = (int*)((char*)d_ws + RP_OFF);
  unsigned short* ms = (unsigned short*)((char*)d_ws + MS_OFF);

  int setup_items = (N + 1) > WP_ELEMS ? (N + 1) : WP_ELEMS;
  setup_kernel<<<(setup_items + 255) / 256, 256, 0, stream>>>(We, be, dst, wp, rp, E, N);

  int ntiles = (E + 15) / 16;
  int blocksA = min(NBLK, (ntiles + 3) / 4);
  edge_gemm_kernel<<<blocksA, 256, 0, stream>>>(feat, efeat, src, wp, ms, E);

  int blocksB = (N + 15) / 16;
  segsum_kernel<<<blocksB, 256, 0, stream>>>(feat, bias, ms, rp, out, N);
}